// Round 4
// baseline (1049.863 us; speedup 1.0000x reference)
//
#include <hip/hip_runtime.h>
#include <math.h>

#define T_STEPS 256
#define BATCH   256
#define DDIM    128
#define NH      10

typedef float v2f __attribute__((ext_vector_type(2)));
__device__ __forceinline__ v2f sp(float x){ v2f r; r.x = x; r.y = x; return r; }
#define PKFMA(a,b,c) __builtin_elementwise_fma((a),(b),(c))

// ---------- DPP helpers (VALU pipe) ----------
template<int CTRL, int RMASK, int BMASK>
__device__ __forceinline__ float dppz(float x){
  return __int_as_float(__builtin_amdgcn_update_dpp(
      0, __float_as_int(x), CTRL, RMASK, BMASK, true));
}
template<int CTRL>
__device__ __forceinline__ float qperm(float x){
  int xi = __float_as_int(x);
  return __int_as_float(__builtin_amdgcn_update_dpp(xi, xi, CTRL, 0xF, 0xF, false));
}
__device__ __forceinline__ float qp2(float x){ return qperm<0x4E>(x); }  // quad xor2
__device__ __forceinline__ float qp1(float x){ return qperm<0xB1>(x); }  // quad xor1

__device__ __forceinline__ float rdlane(float v, int l){
  return __int_as_float(__builtin_amdgcn_readlane(__float_as_int(v), l));
}

// ---------- signed ladder stages (totals land at lane 63; proven R4+) ----------
template<int CTRL,int RMASK,int BMASK>
__device__ __forceinline__ float lad_add(float v){ return v + dppz<CTRL,RMASK,BMASK>(v); }
template<int CTRL,int RMASK,int BMASK>
__device__ __forceinline__ float lad_sub(float v){ return dppz<CTRL,RMASK,BMASK>(v) - v; }
#define LAD0_A(v) lad_add<0x111,0xF,0xF>(v)
#define LAD0_S(v) lad_sub<0x111,0xF,0xF>(v)
#define LAD1_A(v) lad_add<0x112,0xF,0xF>(v)
#define LAD1_S(v) lad_sub<0x112,0xF,0xF>(v)
#define LAD2_A(v) lad_add<0x114,0xF,0xE>(v)
#define LAD2_S(v) lad_sub<0x114,0xF,0xE>(v)
#define LAD3_A(v) lad_add<0x118,0xF,0xC>(v)
#define LAD3_S(v) lad_sub<0x118,0xF,0xC>(v)
#define LAD4_A(v) lad_add<0x142,0xA,0xF>(v)
#define LAD4_S(v) lad_sub<0x142,0xA,0xF>(v)
#define LAD5_A(v) lad_add<0x143,0xC,0xF>(v)
#define LAD5_S(v) lad_sub<0x143,0xC,0xF>(v)

// ---------- ds-pipe xor fetchers ----------
__device__ __forceinline__ float dsx32(float x){ return __shfl_xor(x, 32, 64); }
__device__ __forceinline__ float dsx16(float x){
  return __int_as_float(__builtin_amdgcn_ds_swizzle(__float_as_int(x), 0x401F));
}
__device__ __forceinline__ float dsx8(float x){
  return __int_as_float(__builtin_amdgcn_ds_swizzle(__float_as_int(x), 0x201F));
}
__device__ __forceinline__ float dsx4(float x){
  return __int_as_float(__builtin_amdgcn_ds_swizzle(__float_as_int(x), 0x101F));
}

// ---------- multi-value wave reductions (merge tree) ----------
// Butterfly xor stages 32..1; after each stage values merge into disjoint
// lane blocks via cndmask. Every value passes through all 6 xor widths, so
// its block holds the full 64-lane sum. Placement: v0@lane0, v1@lane32,
// v2@lane16.
__device__ __forceinline__ void tree3(float v0, float v1, float v2,
                                      int l5, int l4,
                                      float& t0, float& t1, float& t2){
  float a = v0 + dsx32(v0);
  float b = v1 + dsx32(v1);
  float c = v2 + dsx32(v2);
  float m = l5 ? b : a;
  m += dsx16(m);
  c += dsx16(c);
  float m2 = l4 ? c : m;
  m2 += dsx8(m2);
  m2 += dsx4(m2);
  m2 += qp2(m2);
  m2 += qp1(m2);
  t0 = rdlane(m2, 0);
  t1 = rdlane(m2, 32);
  t2 = rdlane(m2, 16);
}
__device__ __forceinline__ void tree2(float v0, float v1, int l5,
                                      float& t0, float& t1){
  float a = v0 + dsx32(v0);
  float b = v1 + dsx32(v1);
  float m = l5 ? b : a;
  m += dsx16(m);
  m += dsx8(m);
  m += dsx4(m);
  m += qp2(m);
  m += qp1(m);
  t0 = rdlane(m, 0);
  t1 = rdlane(m, 32);
}

#define NK 2   // 2 packed pairs = 4 complex amps per lane (quarter statevector)

// RX on a lane-bit wire, packed.
#define RX_LANE_PK(FETCH, cv, sv)                                              \
  { const v2f cc_ = sp(cv), ss_ = sp(sv);                                      \
    _Pragma("unroll")                                                          \
    for (int k = 0; k < NK; ++k){                                              \
      v2f oa, ob;                                                              \
      oa.x = FETCH(RE[k].x); oa.y = FETCH(RE[k].y);                            \
      ob.x = FETCH(IM[k].x); ob.y = FETCH(IM[k].y);                            \
      RE[k] = PKFMA(cc_, RE[k], ss_ * ob);                                     \
      IM[k] = PKFMA(cc_, IM[k], -(ss_ * oa));                                  \
    } }

// RX on reg bit R1 (wire 8): partner is the other pair, no component swap.
__device__ __forceinline__ void rx_reg8_pk(float c, float s, v2f* RE, v2f* IM){
  const v2f cc = sp(c), ss = sp(s);
  v2f oR0 = RE[0], oI0 = IM[0], oR1 = RE[1], oI1 = IM[1];
  RE[0] = PKFMA(cc, oR0,  ss * oI1);
  IM[0] = PKFMA(cc, oI0, -(ss * oR1));
  RE[1] = PKFMA(cc, oR1,  ss * oI0);
  IM[1] = PKFMA(cc, oI1, -(ss * oR0));
}
// RX on reg bit R0 (wire 9): partner is the swapped component of same pair.
__device__ __forceinline__ void rx_reg9_pk(float c, float s, v2f* RE, v2f* IM){
  const v2f cc = sp(c), ss = sp(s);
  #pragma unroll
  for (int k = 0; k < NK; ++k){
    v2f oa = __builtin_shufflevector(RE[k], RE[k], 1, 0);
    v2f ob = __builtin_shufflevector(IM[k], IM[k], 1, 0);
    RE[k] = PKFMA(cc, RE[k],  ss * ob);
    IM[k] = PKFMA(cc, IM[k], -(ss * oa));
  }
}

// ================= R4 (16-wave) layout =================
// Block = 1024 threads = 16 waves: 4 gates x 4-wave quad. Each wave holds
// 256 amps = 64 lanes x 4 regs (2 v2f pairs). Bit map: wires 0..5 -> lane
// bits 5..0, wire 6 -> W1 (quad bit1), wire 7 -> W0 (quad bit0),
// wire 8 -> R1 (pair idx), wire 9 -> R0 (packed component).
// Wire-space algebra (verified R1-R7): beta_w = bit_w ^ bit_{w-1} (ring),
// beta0 = b0^b9, beta1 = b0^b1^b9; phase k = sum(beta) mod 4;
// measurement sets S_0={1..9}, S_w={0..w}.
// New-bit betas: b0=L5^R0 b1=L5^L4^R0 b2=L4^L3 b3=L3^L2 b4=L2^L1 b5=L1^L0
//                b6=L0^W1 b7=W1^W0 b8=W0^R1 b9=R1^R0
// Measurement lane masks: S1..S5: 0x30,0x38,0x3C,0x3E,0x3F; S6..S9,S0 lane
// part 0x3F (S0: 0x1F); reg part: S8:{R1}, S9/S0:{R1,R0}; wave part:
// S6:{W1}, S7/S8/S9/S0:{W1,W0} -> combine signs per quad index q.
__global__ void __launch_bounds__(1024)
__attribute__((amdgpu_waves_per_eu(4)))
qlstm_kernel(const float* __restrict__ inp, const float* __restrict__ rxp,
             const float* __restrict__ Wf, const float* __restrict__ bf,
             const float* __restrict__ Wi, const float* __restrict__ bi,
             const float* __restrict__ Wg, const float* __restrict__ bg,
             const float* __restrict__ Wo, const float* __restrict__ bo,
             float* __restrict__ out)
{
  const int b    = blockIdx.x;
  const int tid  = threadIdx.x;
  const int wv   = tid >> 6;        // 0..15
  const int g    = wv >> 2;         // gate 0..3 (f,i,g,o)
  const int q    = wv & 3;          // quad index: W1 = q>>1, W0 = q&1
  const int W1   = (q >> 1) & 1;
  const int W0   = q & 1;
  const int lane = tid & 63;

  // wave-wire exchange buffer: [gate][quad][re/im][lane]
  __shared__ float4 Sx[4][4][2][64];
  // measurement partials: partv[q][j].{x,y,z,w} = gate {f,i,g,o}
  __shared__ float4 partv[4][64];
  // angle exchange: csn4[gate][j] packs (cs,sn) for wires 2j, 2j+1
  __shared__ float4 csn4[4][5];
  ((float*)partv)[tid] = 0.f;       // 4*64*4 = 1024 = blockDim

  const float* Wp = (g == 0) ? Wf : (g == 1) ? Wi : (g == 2) ? Wg : Wo;
  const float* bp = (g == 0) ? bf : (g == 1) ? bi : (g == 2) ? bg : bo;

  // Angle duty split across the quad: q0:{0,1,2} q1:{3,4,5} q2:{6,7} q3:{8,9}
  const int cnt   = (q < 2) ? 3 : 2;
  const int wbase = (q < 2) ? 3*q : 6 + 2*(q - 2);

  // Pre-scale weights by 0.5 (half-angle) * 1/(2pi) (v_sin/v_cos take
  // revolutions).
  const float WSC = 0.07957747154594767f;   // 1/(4*pi)
  float wa[3], wb[3], wc[3], bq[3];
  #pragma unroll
  for (int j = 0; j < 3; ++j){
    if (j < cnt){
      const int w = wbase + j;
      wa[j] = WSC * Wp[w*138 + lane];
      wb[j] = WSC * Wp[w*138 + 64 + lane];
      wc[j] = (lane < NH) ? WSC * Wp[w*138 + 128 + lane] : 0.f;
      bq[j] = WSC * (bp[w] + rxp[w]);
    } else { wa[j] = wb[j] = wc[j] = bq[j] = 0.f; }
  }

  float pc[NH], ps[NH];
  #pragma unroll
  for (int w = 0; w < NH; ++w){
    float th = 0.5f * rxp[w];
    pc[w] = cosf(th);
    ps[w] = sinf(th);
  }
  // wire-6/7 composite coefficients (wave-invariant)
  const float cc67 = pc[6]*pc[7], cs67 = pc[6]*ps[7];
  const float sc67 = ps[6]*pc[7], ss67 = ps[6]*ps[7];

  // ---- hoisted lane/wave constants ----
  const int l5 = (lane>>5)&1, l4 = (lane>>4)&1, l3 = (lane>>3)&1;
  const int l2 = (lane>>2)&1, l1 = (lane>>1)&1, l0 = lane&1;
  const int pb2 = l4^l3, pb3 = l3^l2, pb4 = l2^l1, pb5 = l1^l0;
  const int a0 = l5, a1 = l5^l4;
  const int a6w = l0 ^ W1;                         // beta6
  const int w17 = W1 ^ W0;                         // beta7 (wave const)
  const int n_base = pb2 + pb3 + pb4 + pb5 + a6w;

  // phase constants (-i)^k per amp (step-invariant), packed over R0
  v2f CRE[NK], CIM[NK];
  #pragma unroll
  for (int r = 0; r < 2*NK; ++r){
    const int R0 = r&1, R1 = (r>>1)&1;
    int k = (n_base + (a0^R0) + (a1^R0) + w17 + (W0^R1) + (R1^R0)) & 3;
    float cr = (k==0) ? 1.f : (k==2) ? -1.f : 0.f;
    float ci = (k==1) ? -1.f : (k==3) ? 1.f : 0.f;
    if (R0){ CRE[r>>1].y = cr; CIM[r>>1].y = ci; }
    else   { CRE[r>>1].x = cr; CIM[r>>1].x = ci; }
  }

  // combine wave-signs per lane j (hidden unit): sgq = sign of quad q partial
  // S6:{W1} -> q2,q3 minus only for j=6; S7/S8/S9/S0:{W1,W0} -> q1,q2 minus.
  const float sg1 = (lane == 0 || lane >= 7) ? -1.f : 1.f;
  const float sg2 = (lane == 0 || lane >= 6) ? -1.f : 1.f;
  const float sg3 = (lane == 6) ? -1.f : 1.f;

  float h = 0.f, c = 0.f;   // lane j holds h_j, c_j redundantly in every wave

  const float* x0 = inp + (size_t)b * DDIM;
  float xa = x0[lane];
  float xb = x0[64 + lane];

  __syncthreads();

  #pragma unroll 1
  for (int t = 0; t < T_STEPS; ++t){
    float xaC = xa, xbC = xb;
    if (t + 1 < T_STEPS){
      const float* nx = inp + ((size_t)(t+1) * BATCH + b) * DDIM;
      xa = nx[lane];
      xb = nx[64 + lane];
    }

    // ---- gate pre-activation angles: each quad wave computes its wires ----
    {
      float v0 = fmaf(xaC, wa[0], fmaf(xbC, wb[0], h * wc[0]));
      float v1 = fmaf(xaC, wa[1], fmaf(xbC, wb[1], h * wc[1]));
      float t0, t1, t2 = 0.f;
      if (cnt == 3){
        float v2 = fmaf(xaC, wa[2], fmaf(xbC, wb[2], h * wc[2]));
        tree3(v0, v1, v2, l5, l4, t0, t1, t2);
      } else {
        tree2(v0, v1, l5, t0, t1);
      }
      t0 += bq[0]; t1 += bq[1]; t2 += bq[2];
      float c0 = __builtin_amdgcn_cosf(t0), s0 = __builtin_amdgcn_sinf(t0);
      float c1 = __builtin_amdgcn_cosf(t1), s1 = __builtin_amdgcn_sinf(t1);
      float c2 = __builtin_amdgcn_cosf(t2), s2 = __builtin_amdgcn_sinf(t2);
      if (lane == 0){
        float2* c2p = (float2*)&csn4[g][0];
        c2p[wbase]     = make_float2(c0, s0);
        c2p[wbase + 1] = make_float2(c1, s1);
        if (cnt == 3) c2p[wbase + 2] = make_float2(c2, s2);
      }
    }
    __syncthreads();   // barrier A: angle publish
    float cs[NH], sn[NH];
    #pragma unroll
    for (int j = 0; j < 5; ++j){
      float4 cw = csn4[g][j];
      cs[2*j]   = cw.x; sn[2*j]   = cw.y;
      cs[2*j+1] = cw.z; sn[2*j+1] = cw.w;
    }

    // ---- build quarter-statevector ----
    float f2 = pb2 ? sn[2] : cs[2];
    float f3 = pb3 ? sn[3] : cs[3];
    float f4 = pb4 ? sn[4] : cs[4];
    float f5 = pb5 ? sn[5] : cs[5];
    float m2345 = ((f2*f3)*(f4*f5)) * (a6w ? sn[6] : cs[6]);

    float q0 = (a0 ? sn[0] : cs[0]) * (a1 ? sn[1] : cs[1]);
    float q1 = (a0 ? cs[0] : sn[0]) * (a1 ? cs[1] : sn[1]);
    v2f ZZ; ZZ.x = m2345 * q0; ZZ.y = m2345 * q1;

    float f7  = w17 ? sn[7] : cs[7];                 // beta7 wave const
    float t8a = f7 * (W0 ? sn[8] : cs[8]);           // k=0: beta8 = W0
    float t8b = f7 * (W0 ? cs[8] : sn[8]);           // k=1: beta8 = !W0
    v2f s9a; s9a.x = cs[9]; s9a.y = sn[9];           // k=0: beta9 = R0
    v2f s9b; s9b.x = sn[9]; s9b.y = cs[9];           // k=1: beta9 = !R0

    v2f RE[NK], IM[NK];
    {
      v2f M0 = (sp(t8a) * s9a) * ZZ;
      v2f M1 = (sp(t8b) * s9b) * ZZ;
      RE[0] = M0 * CRE[0]; IM[0] = M0 * CIM[0];
      RE[1] = M1 * CRE[1]; IM[1] = M1 * CIM[1];
    }

    // ---- RX(p): lane wires 0..5, reg wires 8,9 ----
    RX_LANE_PK(dsx32, pc[0], ps[0])
    RX_LANE_PK(dsx16, pc[1], ps[1])
    RX_LANE_PK(dsx8,  pc[2], ps[2])
    RX_LANE_PK(dsx4,  pc[3], ps[3])
    RX_LANE_PK(qp2,   pc[4], ps[4])
    RX_LANE_PK(qp1,   pc[5], ps[5])
    rx_reg8_pk(pc[8], ps[8], RE, IM);
    rx_reg9_pk(pc[9], ps[9], RE, IM);

    // ---- wires 6,7 (quad bits): single 4-way LDS exchange ----
    Sx[g][q][0][lane] = make_float4(RE[0].x, RE[0].y, RE[1].x, RE[1].y);
    Sx[g][q][1][lane] = make_float4(IM[0].x, IM[0].y, IM[1].x, IM[1].y);
    __syncthreads();   // barrier B
    {
      float4 r1 = Sx[g][q^1][0][lane], i1 = Sx[g][q^1][1][lane];  // X7 (W0)
      float4 r2 = Sx[g][q^2][0][lane], i2 = Sx[g][q^2][1][lane];  // X6 (W1)
      float4 r3 = Sx[g][q^3][0][lane], i3 = Sx[g][q^3][1][lane];  // X6X7
      v2f R1v[2], I1v[2], R2v[2], I2v[2], R3v[2], I3v[2];
      R1v[0].x = r1.x; R1v[0].y = r1.y; R1v[1].x = r1.z; R1v[1].y = r1.w;
      I1v[0].x = i1.x; I1v[0].y = i1.y; I1v[1].x = i1.z; I1v[1].y = i1.w;
      R2v[0].x = r2.x; R2v[0].y = r2.y; R2v[1].x = r2.z; R2v[1].y = r2.w;
      I2v[0].x = i2.x; I2v[0].y = i2.y; I2v[1].x = i2.z; I2v[1].y = i2.w;
      R3v[0].x = r3.x; R3v[0].y = r3.y; R3v[1].x = r3.z; R3v[1].y = r3.w;
      I3v[0].x = i3.x; I3v[0].y = i3.y; I3v[1].x = i3.z; I3v[1].y = i3.w;
      const v2f vcc = sp(cc67), vcs = sp(cs67), vsc = sp(sc67), vss = sp(ss67);
      #pragma unroll
      for (int k = 0; k < NK; ++k){
        v2f nre = PKFMA(vcc, RE[k],
                  PKFMA(vcs, I1v[k],
                  PKFMA(vsc, I2v[k], -(vss * R3v[k]))));
        v2f nim = PKFMA(vcc, IM[k],
                  -(PKFMA(vcs, R1v[k],
                    PKFMA(vsc, R2v[k], vss * I3v[k]))));
        RE[k] = nre; IM[k] = nim;
      }
    }

    // ---- PauliZ partials ----
    v2f Pk0 = PKFMA(RE[0], RE[0], IM[0]*IM[0]);
    v2f Pk1 = PKFMA(RE[1], RE[1], IM[1]*IM[1]);
    float A0 = Pk0.x + Pk0.y, A1 = Pk1.x + Pk1.y;
    float B0 = Pk0.x - Pk0.y, B1 = Pk1.x - Pk1.y;
    float tot = A0 + A1;      // no reg sign
    float qA  = A0 - A1;      // sign on R1      (unit 8)
    float qB  = B0 - B1;      // sign on R1^R0   (units 9, 0)

    // tot-family: units 1..5 lane masks 0x30,0x38,0x3C,0x3E,0x3F (shared tree)
    float a0p = LAD0_A(tot);
    float a0m = LAD0_S(tot);
    float b1pp = LAD1_A(a0p);
    float b1pm = LAD1_S(a0p);
    float b1mm = LAD1_S(a0m);
    float c2ppp = LAD2_A(b1pp);
    float c2ppm = LAD2_S(b1pp);
    float c2pmm = LAD2_S(b1pm);
    float c2mmm = LAD2_S(b1mm);
    float d1 = LAD3_A(c2ppp);
    float d2 = LAD3_S(c2ppp);
    float d3 = LAD3_S(c2ppm);
    float d4 = LAD3_S(c2pmm);
    float d5 = LAD3_S(c2mmm);
    float P1 = LAD5_S(LAD4_S(d1));
    float P2 = LAD5_S(LAD4_S(d2));
    float P3 = LAD5_S(LAD4_S(d3));
    float P4 = LAD5_S(LAD4_S(d4));
    float P5 = LAD5_S(LAD4_S(d5));   // serves units 5,6,7 (wave signs differ)
    // qB: unit 9 = all-minus 0x3F; unit 0 = 0x1F minus + bit5 plus (shared)
    float e = LAD0_S(qB);
    e = LAD1_S(e); e = LAD2_S(e); e = LAD3_S(e); e = LAD4_S(e);
    float P9 = LAD5_S(e);
    float P0 = LAD5_A(e);
    // qA: unit 8 = all-minus
    float f_ = LAD0_S(qA);
    f_ = LAD1_S(f_); f_ = LAD2_S(f_); f_ = LAD3_S(f_); f_ = LAD4_S(f_);
    float P8 = LAD5_S(f_);

    if (lane == 63){
      float vals[10] = {P0, P1, P2, P3, P4, P5, P5, P5, P8, P9};
      #pragma unroll
      for (int j = 0; j < 10; ++j)
        ((float*)&partv[q][j])[g] = vals[j];
    }
    __syncthreads();   // barrier C: measurement partials

    // ---- combine partials + activations + cell (every lane, every wave) ----
    float4 e0 = partv[0][lane];
    float4 e1 = partv[1][lane];
    float4 e2 = partv[2][lane];
    float4 e3 = partv[3][lane];
    float E0 = fmaf(sg3, e3.x, fmaf(sg2, e2.x, fmaf(sg1, e1.x, e0.x)));
    float E1 = fmaf(sg3, e3.y, fmaf(sg2, e2.y, fmaf(sg1, e1.y, e0.y)));
    float E2 = fmaf(sg3, e3.z, fmaf(sg2, e2.z, fmaf(sg1, e1.z, e0.z)));
    float E3 = fmaf(sg3, e3.w, fmaf(sg2, e2.w, fmaf(sg1, e1.w, e0.w)));
    float fv = 1.f / (1.f + __expf(-E0));
    float iv = 1.f / (1.f + __expf(-E1));
    float e2g = __expf(2.f * E2);
    float gv = (e2g - 1.f) / (e2g + 1.f);
    float ov = 1.f / (1.f + __expf(-E3));
    c = fmaf(fv, c, iv * gv);
    float e2c = __expf(2.f * c);
    h = ov * ((e2c - 1.f) / (e2c + 1.f));

    if (wv == 0 && lane < NH)
      out[((size_t)t * BATCH + b) * NH + lane] = h;
  }

  // hT, cT
  if (wv == 0 && lane < NH){
    const size_t ysN = (size_t)T_STEPS * BATCH * NH;
    out[ysN + (size_t)b * NH + lane]                      = h;
    out[ysN + (size_t)BATCH * NH + (size_t)b * NH + lane] = c;
  }
}

extern "C" void kernel_launch(void* const* d_in, const int* in_sizes, int n_in,
                              void* d_out, int out_size, void* d_ws, size_t ws_size,
                              hipStream_t stream)
{
  qlstm_kernel<<<BATCH, 1024, 0, stream>>>(
      (const float*)d_in[0], (const float*)d_in[1],
      (const float*)d_in[2], (const float*)d_in[3],
      (const float*)d_in[4], (const float*)d_in[5],
      (const float*)d_in[6], (const float*)d_in[7],
      (const float*)d_in[8], (const float*)d_in[9],
      (float*)d_out);
}

// Round 5
// 879.638 us; speedup vs baseline: 1.1935x; 1.1935x over previous
//
#include <hip/hip_runtime.h>
#include <math.h>

#define T_STEPS 256
#define BATCH   256
#define DDIM    128
#define NH      10

typedef float v2f __attribute__((ext_vector_type(2)));
__device__ __forceinline__ v2f sp(float x){ v2f r; r.x = x; r.y = x; return r; }
#define PKFMA(a,b,c) __builtin_elementwise_fma((a),(b),(c))

// ---------- DPP helpers (VALU pipe) ----------
template<int CTRL, int RMASK, int BMASK>
__device__ __forceinline__ float dppz(float x){
  return __int_as_float(__builtin_amdgcn_update_dpp(
      0, __float_as_int(x), CTRL, RMASK, BMASK, true));
}
template<int CTRL>
__device__ __forceinline__ float qperm(float x){
  int xi = __float_as_int(x);
  return __int_as_float(__builtin_amdgcn_update_dpp(xi, xi, CTRL, 0xF, 0xF, false));
}
// Canonical wave64 ladder (proven R4+): lane 63 ends with the full sum.
__device__ __forceinline__ float red63(float v){
  v += dppz<0x111, 0xF, 0xF>(v);
  v += dppz<0x112, 0xF, 0xF>(v);
  v += dppz<0x114, 0xF, 0xE>(v);
  v += dppz<0x118, 0xF, 0xC>(v);
  v += dppz<0x142, 0xA, 0xF>(v);
  v += dppz<0x143, 0xC, 0xF>(v);
  return v;
}
__device__ __forceinline__ float rdlane(float v, int l){
  return __int_as_float(__builtin_amdgcn_readlane(__float_as_int(v), l));
}
__device__ __forceinline__ float qp2(float x){ return qperm<0x4E>(x); }  // quad xor2
__device__ __forceinline__ float qp1(float x){ return qperm<0xB1>(x); }  // quad xor1

// ---------- signed ladder stages (totals land at lane 63; proven R3) ----------
template<int CTRL,int RMASK,int BMASK>
__device__ __forceinline__ float lad_add(float v){ return v + dppz<CTRL,RMASK,BMASK>(v); }
template<int CTRL,int RMASK,int BMASK>
__device__ __forceinline__ float lad_sub(float v){ return dppz<CTRL,RMASK,BMASK>(v) - v; }
#define LAD0_A(v) lad_add<0x111,0xF,0xF>(v)
#define LAD0_S(v) lad_sub<0x111,0xF,0xF>(v)
#define LAD1_A(v) lad_add<0x112,0xF,0xF>(v)
#define LAD1_S(v) lad_sub<0x112,0xF,0xF>(v)
#define LAD2_A(v) lad_add<0x114,0xF,0xE>(v)
#define LAD2_S(v) lad_sub<0x114,0xF,0xE>(v)
#define LAD3_A(v) lad_add<0x118,0xF,0xC>(v)
#define LAD3_S(v) lad_sub<0x118,0xF,0xC>(v)
#define LAD4_A(v) lad_add<0x142,0xA,0xF>(v)
#define LAD4_S(v) lad_sub<0x142,0xA,0xF>(v)
#define LAD5_A(v) lad_add<0x143,0xC,0xF>(v)
#define LAD5_S(v) lad_sub<0x143,0xC,0xF>(v)

// ---------- ds-pipe xor fetchers (offload from the saturated VALU) ----------
__device__ __forceinline__ float dsx32(float x){ return __shfl_xor(x, 32, 64); }
__device__ __forceinline__ float dsx16(float x){
  return __int_as_float(__builtin_amdgcn_ds_swizzle(__float_as_int(x), 0x401F));
}
__device__ __forceinline__ float dsx8(float x){
  return __int_as_float(__builtin_amdgcn_ds_swizzle(__float_as_int(x), 0x201F));
}
__device__ __forceinline__ float dsx4(float x){
  return __int_as_float(__builtin_amdgcn_ds_swizzle(__float_as_int(x), 0x101F));
}

#define NK 4   // 4 packed pairs = 8 complex amps per lane (half statevector)

// RX on a lane-bit wire, packed: 2 fetches + 2 pk ops per pair.
#define RX_LANE_PK(FETCH, cv, sv)                                              \
  { const v2f cc_ = sp(cv), ss_ = sp(sv);                                      \
    _Pragma("unroll")                                                          \
    for (int k = 0; k < NK; ++k){                                              \
      v2f oa, ob;                                                              \
      oa.x = FETCH(RE[k].x); oa.y = FETCH(RE[k].y);                            \
      ob.x = FETCH(IM[k].x); ob.y = FETCH(IM[k].y);                            \
      RE[k] = PKFMA(cc_, RE[k], ss_ * ob);                                     \
      IM[k] = PKFMA(cc_, IM[k], -(ss_ * oa));                                  \
    } }

// RX on reg bit R2 (XB=2) / R1 (XB=1): partner pair is k^XB, no component swap.
template<int XB>
__device__ __forceinline__ void rx_reg_pk(float c, float s, v2f* RE, v2f* IM){
  const v2f cc = sp(c), ss = sp(s);
  v2f oR[NK], oI[NK];
  #pragma unroll
  for (int k = 0; k < NK; ++k){ oR[k] = RE[k]; oI[k] = IM[k]; }
  #pragma unroll
  for (int k = 0; k < NK; ++k){
    RE[k] = PKFMA(cc, oR[k],  ss * oI[k ^ XB]);
    IM[k] = PKFMA(cc, oI[k], -(ss * oR[k ^ XB]));
  }
}
// RX on reg bit R0: partner is the swapped component of the same pair.
__device__ __forceinline__ void rx_reg9_pk(float c, float s, v2f* RE, v2f* IM){
  const v2f cc = sp(c), ss = sp(s);
  #pragma unroll
  for (int k = 0; k < NK; ++k){
    v2f oa = __builtin_shufflevector(RE[k], RE[k], 1, 0);
    v2f ob = __builtin_shufflevector(IM[k], IM[k], 1, 0);
    RE[k] = PKFMA(cc, RE[k],  ss * ob);
    IM[k] = PKFMA(cc, IM[k], -(ss * oa));
  }
}

// x-part dot products for the 5 owned wires: totals land at lane 63.
__device__ __forceinline__ void xdots(float xa, float xb,
                                      const v2f* WA, const v2f* WB, float* s){
  v2f xav = sp(xa), xbv = sp(xb);
  v2f p0 = PKFMA(xav, WA[0], xbv * WB[0]);
  v2f p1 = PKFMA(xav, WA[1], xbv * WB[1]);
  v2f p2 = PKFMA(xav, WA[2], xbv * WB[2]);
  s[0] = red63(p0.x); s[1] = red63(p0.y);
  s[2] = red63(p1.x); s[3] = red63(p1.y);
  s[4] = red63(p2.x);
}

// ================= R8 layout (verified algebra, unchanged) =================
// Wave pair per gate: 512 amps/wave = 64 lanes x 8 regs (4 v2f pairs).
// Wires 0..5 -> lane bits 5..0, wire 6 -> wave bit (LDS exchange),
// wires 7,8,9 -> reg bits 2,1,0 (R0 = packed component).
// Angle path (new R5): x-parts (incl. bias) published via LDS at barrier C
// (computed one step ahead in the barrier-B shadow); h-part + trig computed
// lane-parallel (lane = wire) from readlane(h, j) broadcasts. 2 barriers/step.
__global__ void __launch_bounds__(512)
__attribute__((amdgpu_waves_per_eu(2)))
qlstm_kernel(const float* __restrict__ inp, const float* __restrict__ rxp,
             const float* __restrict__ Wf, const float* __restrict__ bf,
             const float* __restrict__ Wi, const float* __restrict__ bi,
             const float* __restrict__ Wg, const float* __restrict__ bg,
             const float* __restrict__ Wo, const float* __restrict__ bo,
             float* __restrict__ out)
{
  const int b    = blockIdx.x;
  const int tid  = threadIdx.x;
  const int wv   = tid >> 6;        // 0..7
  const int g    = wv >> 1;         // gate 0..3 (f,i,g,o)
  const int half = wv & 1;          // statevector half (wire-6 / wave bit)
  const int lane = tid & 63;

  // wire-6 exchange buffer: [gate][half][chunk][lane]
  __shared__ float4 Sx[4][2][4][64];
  // measurement partials, transposed: partv[half][j].{x,y,z,w} = gate f,i,g,o
  __shared__ float4 partv[2][64];
  // published x-part pre-activations (incl. bias), xpub_s[g][wire]
  __shared__ float xpub_s[4][16];
  ((float*)partv)[tid] = 0.f;       // 2*64*4 = 512 = blockDim

  const float* Wp = (g == 0) ? Wf : (g == 1) ? Wi : (g == 2) ? Wg : Wo;
  const float* bp = (g == 0) ? bf : (g == 1) ? bi : (g == 2) ? bg : bo;

  // Pre-scale weights by 0.5 (half-angle) * 1/(2pi) (v_sin/v_cos take
  // revolutions).
  const float WSC = 0.07957747154594767f;   // 1/(4*pi)

  // x-dot weights for this half's 5 owned wires (wbase..wbase+4)
  const int wbase = half * 5;
  v2f WA[3], WB[3];
  float bq[5];
  #pragma unroll
  for (int k = 0; k < 5; ++k) bq[k] = WSC * (bp[wbase + k] + rxp[wbase + k]);
  #pragma unroll
  for (int j = 0; j < 3; ++j){
    const int w0 = wbase + 2*j, w1 = wbase + 2*j + 1;
    WA[j].x = WSC * Wp[w0*138 + lane];
    WB[j].x = WSC * Wp[w0*138 + 64 + lane];
    if (2*j + 1 < 5){
      WA[j].y = WSC * Wp[w1*138 + lane];
      WB[j].y = WSC * Wp[w1*138 + 64 + lane];
    } else { WA[j].y = 0.f; WB[j].y = 0.f; }
  }
  // transposed h-weights: lane w holds W[w][128+j] (hdot computed lane-parallel)
  float wCT[NH];
  {
    const int row = (lane < NH) ? lane : 0;
    #pragma unroll
    for (int j = 0; j < NH; ++j){
      float v = WSC * Wp[row*138 + 128 + j];
      wCT[j] = (lane < NH) ? v : 0.f;
    }
  }

  float pc[NH], ps[NH];
  #pragma unroll
  for (int w = 0; w < NH; ++w){
    float th = 0.5f * rxp[w];
    pc[w] = cosf(th);
    ps[w] = sinf(th);
  }

  // ---- hoisted lane/wave constants ----
  const int l5 = (lane>>5)&1, l4 = (lane>>4)&1, l3 = (lane>>3)&1;
  const int l2 = (lane>>2)&1, l1 = (lane>>1)&1, l0 = lane&1;
  const int pb2 = l4^l3, pb3 = l3^l2, pb4 = l2^l1, pb5 = l1^l0;
  const int a0 = l5, a1 = l5^l4;
  const int a6w = l0 ^ half;                       // beta6
  const int n_base = pb2 + pb3 + pb4 + pb5 + a6w;

  // phase constants (-i)^k per reg (step-invariant), packed over R0
  v2f CRE[NK], CIM[NK];
  #pragma unroll
  for (int r = 0; r < 2*NK; ++r){
    const int R0 = r&1, R1 = (r>>1)&1, R2 = (r>>2)&1;
    int k = (n_base + (a0^R0) + (a1^R0) + (half^R2) + (R2^R1) + (R1^R0)) & 3;
    float cr = (k==0) ? 1.f : (k==2) ? -1.f : 0.f;
    float ci = (k==1) ? -1.f : (k==3) ? 1.f : 0.f;
    if (R0){ CRE[r>>1].y = cr; CIM[r>>1].y = ci; }
    else   { CRE[r>>1].x = cr; CIM[r>>1].x = ci; }
  }

  // wave-sign at combine: sigma = -1 for hidden units {0, 6..9}
  const float sig = (lane == 0 || lane >= 6) ? -1.f : 1.f;

  float h = 0.f, c = 0.f;   // lane j holds h_j, c_j redundantly in every wave

  const float* x0 = inp + (size_t)b * DDIM;
  float xa = x0[lane];
  float xb = x0[64 + lane];

  // publish x-part pre-activations for step 0
  {
    float sx[5];
    xdots(xa, xb, WA, WB, sx);
    if (lane == 63){
      #pragma unroll
      for (int k = 0; k < 5; ++k) xpub_s[g][wbase + k] = sx[k] + bq[k];
    }
  }
  __syncthreads();

  #pragma unroll 1
  for (int t = 0; t < T_STEPS; ++t){
    if (t + 1 < T_STEPS){
      const float* nx = inp + ((size_t)(t+1) * BATCH + b) * DDIM;
      xa = nx[lane];
      xb = nx[64 + lane];
    }

    // ---- angles: lane-parallel (lane = wire). th = xpub + h-dot; ONE
    // v_cos + ONE v_sin cover all 10 wires; broadcast via readlane. ----
    float cs[NH], sn[NH];
    {
      float xr = xpub_s[g][lane & 15];
      float hdA = rdlane(h, 0) * wCT[0];
      float hdB = rdlane(h, 1) * wCT[1];
      hdA = fmaf(rdlane(h, 2), wCT[2], hdA);
      hdB = fmaf(rdlane(h, 3), wCT[3], hdB);
      hdA = fmaf(rdlane(h, 4), wCT[4], hdA);
      hdB = fmaf(rdlane(h, 5), wCT[5], hdB);
      hdA = fmaf(rdlane(h, 6), wCT[6], hdA);
      hdB = fmaf(rdlane(h, 7), wCT[7], hdB);
      hdA = fmaf(rdlane(h, 8), wCT[8], hdA);
      hdB = fmaf(rdlane(h, 9), wCT[9], hdB);
      float th = xr + (hdA + hdB);
      float cA = __builtin_amdgcn_cosf(th);
      float sA = __builtin_amdgcn_sinf(th);
      #pragma unroll
      for (int w = 0; w < NH; ++w){
        cs[w] = rdlane(cA, w);
        sn[w] = rdlane(sA, w);
      }
    }

    // ---- build half-statevector: u[j] = prod-state(x+p) at K j ----
    float f2 = pb2 ? sn[2] : cs[2];
    float f3 = pb3 ? sn[3] : cs[3];
    float f4 = pb4 ? sn[4] : cs[4];
    float f5 = pb5 ? sn[5] : cs[5];
    float m2345 = ((f2*f3)*(f4*f5)) * (a6w ? sn[6] : cs[6]);

    float q0 = (a0 ? sn[0] : cs[0]) * (a1 ? sn[1] : cs[1]);
    float q1 = (a0 ? cs[0] : sn[0]) * (a1 ? cs[1] : sn[1]);
    v2f ZZ; ZZ.x = m2345 * q0; ZZ.y = m2345 * q1;

    float u7  = half ? sn[7] : cs[7];
    float u7b = half ? cs[7] : sn[7];
    float t78[4];
    t78[0] = u7  * cs[8];   // k=0: R2=0,R1=0
    t78[1] = u7  * sn[8];   // k=1: R2=0,R1=1
    t78[2] = u7b * sn[8];   // k=2: R2=1,R1=0
    t78[3] = u7b * cs[8];   // k=3: R2=1,R1=1

    v2f s9a; s9a.x = cs[9]; s9a.y = sn[9];   // k even: b9 = R1^R0 = (0,1)
    v2f s9b; s9b.x = sn[9]; s9b.y = cs[9];   // k odd:  b9 = (1,0)

    v2f RE[NK], IM[NK];
    #pragma unroll
    for (int k = 0; k < NK; ++k){
      v2f M = (sp(t78[k]) * ((k & 1) ? s9b : s9a)) * ZZ;
      RE[k] = M * CRE[k];
      IM[k] = M * CIM[k];
    }

    // ---- RX(p): lane wires 0..5 (ds-pipe fetch for 0..3), reg wires 7..9 ----
    RX_LANE_PK(dsx32, pc[0], ps[0])
    RX_LANE_PK(dsx16, pc[1], ps[1])
    RX_LANE_PK(dsx8,  pc[2], ps[2])
    RX_LANE_PK(dsx4,  pc[3], ps[3])
    RX_LANE_PK(qp2,   pc[4], ps[4])
    RX_LANE_PK(qp1,   pc[5], ps[5])
    rx_reg_pk<2>(pc[7], ps[7], RE, IM);
    rx_reg_pk<1>(pc[8], ps[8], RE, IM);
    rx_reg9_pk  (pc[9], ps[9], RE, IM);

    // wire 6 (wave bit): exchange full half-state with partner wave via LDS
    Sx[g][half][0][lane] = make_float4(RE[0].x, RE[0].y, RE[1].x, RE[1].y);
    Sx[g][half][1][lane] = make_float4(RE[2].x, RE[2].y, RE[3].x, RE[3].y);
    Sx[g][half][2][lane] = make_float4(IM[0].x, IM[0].y, IM[1].x, IM[1].y);
    Sx[g][half][3][lane] = make_float4(IM[2].x, IM[2].y, IM[3].x, IM[3].y);

    // ---- shadow: x-part dots for step t+1 (uses prefetched x) ----
    float sx[5];
    xdots(xa, xb, WA, WB, sx);

    __syncthreads();   // barrier B: wire-6 exchange
    {
      float4 pr0 = Sx[g][half^1][0][lane];
      float4 pr1 = Sx[g][half^1][1][lane];
      float4 pi0 = Sx[g][half^1][2][lane];
      float4 pi1 = Sx[g][half^1][3][lane];
      v2f PR[NK], PI[NK];
      PR[0].x = pr0.x; PR[0].y = pr0.y; PR[1].x = pr0.z; PR[1].y = pr0.w;
      PR[2].x = pr1.x; PR[2].y = pr1.y; PR[3].x = pr1.z; PR[3].y = pr1.w;
      PI[0].x = pi0.x; PI[0].y = pi0.y; PI[1].x = pi0.z; PI[1].y = pi0.w;
      PI[2].x = pi1.x; PI[2].y = pi1.y; PI[3].x = pi1.z; PI[3].y = pi1.w;
      const v2f c6 = sp(pc[6]), s6 = sp(ps[6]);
      #pragma unroll
      for (int k = 0; k < NK; ++k){
        RE[k] = PKFMA(c6, RE[k],  s6 * PI[k]);
        IM[k] = PKFMA(c6, IM[k], -(s6 * PR[k]));
      }
    }

    // ---- PauliZ partials: packed |psi|^2 + shared pair-tree ----
    v2f Pk[NK];
    #pragma unroll
    for (int k = 0; k < NK; ++k) Pk[k] = PKFMA(RE[k], RE[k], IM[k] * IM[k]);
    float A0 = Pk[0].x + Pk[0].y, A1 = Pk[1].x + Pk[1].y;
    float A2 = Pk[2].x + Pk[2].y, A3 = Pk[3].x + Pk[3].y;
    float B0 = Pk[0].x - Pk[0].y, B1 = Pk[1].x - Pk[1].y;
    float B2 = Pk[2].x - Pk[2].y, B3 = Pk[3].x - Pk[3].y;
    float su = A0 + A1, sv = A2 + A3;
    float tot = su + sv;                 // plain sum
    float q4  = su - sv;                 // sign on R2
    float q6  = (A0 - A1) - (A2 - A3);   // sign parity of R2^R1 mask 0x6
    float q7  = (B0 - B1) - (B2 - B3);   // sign parity of mask 0x7

    // ---- shared signed-ladder reductions (sign masks encoded as add/sub) ----
    float a0p = LAD0_A(tot);
    float a0m = LAD0_S(tot);
    float b1pp = LAD1_A(a0p);
    float b1pm = LAD1_S(a0p);
    float b1mm = LAD1_S(a0m);
    float c2ppp = LAD2_A(b1pp);
    float c2ppm = LAD2_S(b1pp);
    float c2pmm = LAD2_S(b1pm);
    float c2mmm = LAD2_S(b1mm);
    float d1 = LAD3_A(c2ppp);   // P1: ++++ then --
    float d2 = LAD3_S(c2ppp);   // P2: +++-
    float d3 = LAD3_S(c2ppm);   // P3: ++--
    float d4 = LAD3_S(c2pmm);   // P4: +---
    float d5 = LAD3_S(c2mmm);   // P5: ----
    float P1 = LAD5_S(LAD4_S(d1));
    float P2 = LAD5_S(LAD4_S(d2));
    float P3 = LAD5_S(LAD4_S(d3));
    float P4 = LAD5_S(LAD4_S(d4));
    float P5 = LAD5_S(LAD4_S(d5));   // serves S5 (sigma +) and S6 (sigma -)
    // q7: P9 = all-minus (mask 0x3F); P0 = minus bits0-4, plus bit5 (0x1F)
    float e = LAD0_S(q7);
    e = LAD1_S(e); e = LAD2_S(e); e = LAD3_S(e); e = LAD4_S(e);
    float P9 = LAD5_S(e);
    float P0 = LAD5_A(e);
    // q4, q6: all-minus (mask 0x3F)
    float f_ = LAD0_S(q4);
    f_ = LAD1_S(f_); f_ = LAD2_S(f_); f_ = LAD3_S(f_); f_ = LAD4_S(f_);
    float P7 = LAD5_S(f_);
    float g_ = LAD0_S(q6);
    g_ = LAD1_S(g_); g_ = LAD2_S(g_); g_ = LAD3_S(g_); g_ = LAD4_S(g_);
    float P8 = LAD5_S(g_);

    if (lane == 63){
      float vals[10] = {P0,P1,P2,P3,P4,P5,P5,P7,P8,P9};
      #pragma unroll
      for (int j = 0; j < 10; ++j)
        ((float*)&partv[half][j])[g] = vals[j];
      #pragma unroll
      for (int k = 0; k < 5; ++k)
        xpub_s[g][wbase + k] = sx[k] + bq[k];
    }
    __syncthreads();   // barrier C: partials + next-step x-parts

    // ---- combine partials + activations + cell (every lane, every wave) ----
    float4 eL = partv[0][lane];
    float4 eH = partv[1][lane];
    float E0 = fmaf(sig, eH.x, eL.x);
    float E1 = fmaf(sig, eH.y, eL.y);
    float E2 = fmaf(sig, eH.z, eL.z);
    float E3 = fmaf(sig, eH.w, eL.w);
    float fv = 1.f / (1.f + __expf(-E0));
    float iv = 1.f / (1.f + __expf(-E1));
    float e2g = __expf(2.f * E2);
    float gv = (e2g - 1.f) / (e2g + 1.f);
    float ov = 1.f / (1.f + __expf(-E3));
    c = fmaf(fv, c, iv * gv);
    float e2c = __expf(2.f * c);
    h = ov * ((e2c - 1.f) / (e2c + 1.f));

    if (wv == 0 && lane < NH)
      out[((size_t)t * BATCH + b) * NH + lane] = h;
  }

  // hT, cT
  if (wv == 0 && lane < NH){
    const size_t ysN = (size_t)T_STEPS * BATCH * NH;
    out[ysN + (size_t)b * NH + lane]                      = h;
    out[ysN + (size_t)BATCH * NH + (size_t)b * NH + lane] = c;
  }
}

extern "C" void kernel_launch(void* const* d_in, const int* in_sizes, int n_in,
                              void* d_out, int out_size, void* d_ws, size_t ws_size,
                              hipStream_t stream)
{
  qlstm_kernel<<<BATCH, 512, 0, stream>>>(
      (const float*)d_in[0], (const float*)d_in[1],
      (const float*)d_in[2], (const float*)d_in[3],
      (const float*)d_in[4], (const float*)d_in[5],
      (const float*)d_in[6], (const float*)d_in[7],
      (const float*)d_in[8], (const float*)d_in[9],
      (float*)d_out);
}

// Round 6
// 788.798 us; speedup vs baseline: 1.3310x; 1.1152x over previous
//
#include <hip/hip_runtime.h>
#include <math.h>

#define T_STEPS 256
#define BATCH   256
#define DDIM    128
#define NH      10

typedef float v2f __attribute__((ext_vector_type(2)));
__device__ __forceinline__ v2f sp(float x){ v2f r; r.x = x; r.y = x; return r; }
#define PKFMA(a,b,c) __builtin_elementwise_fma((a),(b),(c))

// ---------- DPP helpers (VALU pipe) ----------
template<int CTRL, int RMASK, int BMASK>
__device__ __forceinline__ float dppz(float x){
  return __int_as_float(__builtin_amdgcn_update_dpp(
      0, __float_as_int(x), CTRL, RMASK, BMASK, true));
}
// Canonical wave64 ladder (proven R4+): lane 63 ends with the full sum.
__device__ __forceinline__ float red63(float v){
  v += dppz<0x111, 0xF, 0xF>(v);
  v += dppz<0x112, 0xF, 0xF>(v);
  v += dppz<0x114, 0xF, 0xE>(v);
  v += dppz<0x118, 0xF, 0xC>(v);
  v += dppz<0x142, 0xA, 0xF>(v);
  v += dppz<0x143, 0xC, 0xF>(v);
  return v;
}
__device__ __forceinline__ float rdlane(float v, int l){
  return __int_as_float(__builtin_amdgcn_readlane(__float_as_int(v), l));
}

// ---------- signed ladder stages (totals land at lane 63; proven R3) ----------
template<int CTRL,int RMASK,int BMASK>
__device__ __forceinline__ float lad_add(float v){ return v + dppz<CTRL,RMASK,BMASK>(v); }
template<int CTRL,int RMASK,int BMASK>
__device__ __forceinline__ float lad_sub(float v){ return dppz<CTRL,RMASK,BMASK>(v) - v; }
#define LAD0_A(v) lad_add<0x111,0xF,0xF>(v)
#define LAD0_S(v) lad_sub<0x111,0xF,0xF>(v)
#define LAD1_A(v) lad_add<0x112,0xF,0xF>(v)
#define LAD1_S(v) lad_sub<0x112,0xF,0xF>(v)
#define LAD2_A(v) lad_add<0x114,0xF,0xE>(v)
#define LAD2_S(v) lad_sub<0x114,0xF,0xE>(v)
#define LAD3_A(v) lad_add<0x118,0xF,0xC>(v)
#define LAD3_S(v) lad_sub<0x118,0xF,0xC>(v)
#define LAD4_A(v) lad_add<0x142,0xA,0xF>(v)
#define LAD4_S(v) lad_sub<0x142,0xA,0xF>(v)
#define LAD5_A(v) lad_add<0x143,0xC,0xF>(v)
#define LAD5_S(v) lad_sub<0x143,0xC,0xF>(v)

// ---------- ds-pipe xor fetchers (all 6 lane wires on the ds pipe) ----------
// BitMode encodings per ISA doc: xor^{1,2,4,8,16} = 0x041F,0x081F,0x101F,
// 0x201F,0x401F. Bit5 (xor 32) crosses the 32-lane group -> bpermute.
__device__ __forceinline__ float dsx32(float x){ return __shfl_xor(x, 32, 64); }
__device__ __forceinline__ float dsx16(float x){
  return __int_as_float(__builtin_amdgcn_ds_swizzle(__float_as_int(x), 0x401F));
}
__device__ __forceinline__ float dsx8(float x){
  return __int_as_float(__builtin_amdgcn_ds_swizzle(__float_as_int(x), 0x201F));
}
__device__ __forceinline__ float dsx4(float x){
  return __int_as_float(__builtin_amdgcn_ds_swizzle(__float_as_int(x), 0x101F));
}
__device__ __forceinline__ float dsx2(float x){
  return __int_as_float(__builtin_amdgcn_ds_swizzle(__float_as_int(x), 0x081F));
}
__device__ __forceinline__ float dsx1(float x){
  return __int_as_float(__builtin_amdgcn_ds_swizzle(__float_as_int(x), 0x041F));
}

#define NK 4   // 4 packed pairs = 8 complex amps per lane (half statevector)

// ---- tau-form RX (R6): R_w = c_w * T_w; all c_w folded into CRE/CIM at
// init (step-invariant p-angles), so each stage is ONE pk-FMA per output:
//   re' = re + tau*im_partner ; im' = im - tau*re_partner
#define RX_LANE_T(FETCH, tv)                                                   \
  { const v2f tt_ = sp(tv), nt_ = sp(-(tv));                                   \
    _Pragma("unroll")                                                          \
    for (int k = 0; k < NK; ++k){                                              \
      v2f oa, ob;                                                              \
      oa.x = FETCH(RE[k].x); oa.y = FETCH(RE[k].y);                            \
      ob.x = FETCH(IM[k].x); ob.y = FETCH(IM[k].y);                            \
      RE[k] = PKFMA(tt_, ob, RE[k]);                                           \
      IM[k] = PKFMA(nt_, oa, IM[k]);                                           \
    } }

// RX on reg bit R2 (XB=2) / R1 (XB=1): partner pair is k^XB.
template<int XB>
__device__ __forceinline__ void rx_reg_t(float tv, v2f* RE, v2f* IM){
  const v2f tt = sp(tv), nt = sp(-tv);
  v2f oR[NK], oI[NK];
  #pragma unroll
  for (int k = 0; k < NK; ++k){ oR[k] = RE[k]; oI[k] = IM[k]; }
  #pragma unroll
  for (int k = 0; k < NK; ++k){
    RE[k] = PKFMA(tt, oI[k ^ XB], RE[k]);
    IM[k] = PKFMA(nt, oR[k ^ XB], IM[k]);
  }
}
// RX on reg bit R0: partner is the swapped component of the same pair.
__device__ __forceinline__ void rx_reg9_t(float tv, v2f* RE, v2f* IM){
  const v2f tt = sp(tv), nt = sp(-tv);
  #pragma unroll
  for (int k = 0; k < NK; ++k){
    v2f oa = __builtin_shufflevector(RE[k], RE[k], 1, 0);
    v2f ob = __builtin_shufflevector(IM[k], IM[k], 1, 0);
    RE[k] = PKFMA(tt, ob, RE[k]);
    IM[k] = PKFMA(nt, oa, IM[k]);
  }
}

// x-part dot products for the 5 owned wires: totals land at lane 63.
__device__ __forceinline__ void xdots(float xa, float xb,
                                      const v2f* WA, const v2f* WB, float* s){
  v2f xav = sp(xa), xbv = sp(xb);
  v2f p0 = PKFMA(xav, WA[0], xbv * WB[0]);
  v2f p1 = PKFMA(xav, WA[1], xbv * WB[1]);
  v2f p2 = PKFMA(xav, WA[2], xbv * WB[2]);
  s[0] = red63(p0.x); s[1] = red63(p0.y);
  s[2] = red63(p1.x); s[3] = red63(p1.y);
  s[4] = red63(p2.x);
}

// ================= R8 layout (verified algebra, unchanged) =================
// Wave pair per gate: 512 amps/wave = 64 lanes x 8 regs (4 v2f pairs).
// Wires 0..5 -> lane bits 5..0, wire 6 -> wave bit (LDS exchange),
// wires 7,8,9 -> reg bits 2,1,0 (R0 = packed component).
// Angle path (R5): x-parts published via LDS at barrier C (one step ahead,
// in the barrier-B shadow); h-part + trig lane-parallel. 2 barriers/step.
// RX path (R6): tau-form, cosine product PC folded into CRE/CIM.
__global__ void __launch_bounds__(512)
__attribute__((amdgpu_waves_per_eu(2)))
qlstm_kernel(const float* __restrict__ inp, const float* __restrict__ rxp,
             const float* __restrict__ Wf, const float* __restrict__ bf,
             const float* __restrict__ Wi, const float* __restrict__ bi,
             const float* __restrict__ Wg, const float* __restrict__ bg,
             const float* __restrict__ Wo, const float* __restrict__ bo,
             float* __restrict__ out)
{
  const int b    = blockIdx.x;
  const int tid  = threadIdx.x;
  const int wv   = tid >> 6;        // 0..7
  const int g    = wv >> 1;         // gate 0..3 (f,i,g,o)
  const int half = wv & 1;          // statevector half (wire-6 / wave bit)
  const int lane = tid & 63;

  // wire-6 exchange buffer: [gate][half][chunk][lane]
  __shared__ float4 Sx[4][2][4][64];
  // measurement partials, transposed: partv[half][j].{x,y,z,w} = gate f,i,g,o
  __shared__ float4 partv[2][64];
  // published x-part pre-activations (incl. bias), xpub_s[g][wire]
  __shared__ float xpub_s[4][16];
  ((float*)partv)[tid] = 0.f;       // 2*64*4 = 512 = blockDim

  const float* Wp = (g == 0) ? Wf : (g == 1) ? Wi : (g == 2) ? Wg : Wo;
  const float* bp = (g == 0) ? bf : (g == 1) ? bi : (g == 2) ? bg : bo;

  // Pre-scale weights by 0.5 (half-angle) * 1/(2pi) (v_sin/v_cos take
  // revolutions).
  const float WSC = 0.07957747154594767f;   // 1/(4*pi)

  // x-dot weights for this half's 5 owned wires (wbase..wbase+4)
  const int wbase = half * 5;
  v2f WA[3], WB[3];
  float bq[5];
  #pragma unroll
  for (int k = 0; k < 5; ++k) bq[k] = WSC * (bp[wbase + k] + rxp[wbase + k]);
  #pragma unroll
  for (int j = 0; j < 3; ++j){
    const int w0 = wbase + 2*j, w1 = wbase + 2*j + 1;
    WA[j].x = WSC * Wp[w0*138 + lane];
    WB[j].x = WSC * Wp[w0*138 + 64 + lane];
    if (2*j + 1 < 5){
      WA[j].y = WSC * Wp[w1*138 + lane];
      WB[j].y = WSC * Wp[w1*138 + 64 + lane];
    } else { WA[j].y = 0.f; WB[j].y = 0.f; }
  }
  // transposed h-weights: lane w holds W[w][128+j] (hdot computed lane-parallel)
  float wCT[NH];
  {
    const int row = (lane < NH) ? lane : 0;
    #pragma unroll
    for (int j = 0; j < NH; ++j){
      float v = WSC * Wp[row*138 + 128 + j];
      wCT[j] = (lane < NH) ? v : 0.f;
    }
  }

  // tau-form RX constants: tq[w] = tan(rxp[w]/2); PC = prod cos(rxp[w]/2)
  float tq[NH];
  float PC = 1.f;
  #pragma unroll
  for (int w = 0; w < NH; ++w){
    float th = 0.5f * rxp[w];
    float cw = cosf(th), sw = sinf(th);
    PC *= cw;
    tq[w] = sw / cw;
  }

  // ---- hoisted lane/wave constants ----
  const int l5 = (lane>>5)&1, l4 = (lane>>4)&1, l3 = (lane>>3)&1;
  const int l2 = (lane>>2)&1, l1 = (lane>>1)&1, l0 = lane&1;
  const int pb2 = l4^l3, pb3 = l3^l2, pb4 = l2^l1, pb5 = l1^l0;
  const int a0 = l5, a1 = l5^l4;
  const int a6w = l0 ^ half;                       // beta6
  const int n_base = pb2 + pb3 + pb4 + pb5 + a6w;

  // phase constants (-i)^k per reg (step-invariant), packed over R0,
  // scaled by PC (tau-form cosine fold).
  v2f CRE[NK], CIM[NK];
  #pragma unroll
  for (int r = 0; r < 2*NK; ++r){
    const int R0 = r&1, R1 = (r>>1)&1, R2 = (r>>2)&1;
    int k = (n_base + (a0^R0) + (a1^R0) + (half^R2) + (R2^R1) + (R1^R0)) & 3;
    float cr = (k==0) ? PC : (k==2) ? -PC : 0.f;
    float ci = (k==1) ? -PC : (k==3) ? PC : 0.f;
    if (R0){ CRE[r>>1].y = cr; CIM[r>>1].y = ci; }
    else   { CRE[r>>1].x = cr; CIM[r>>1].x = ci; }
  }

  // wave-sign at combine: sigma = -1 for hidden units {0, 6..9}
  const float sig = (lane == 0 || lane >= 6) ? -1.f : 1.f;

  float h = 0.f, c = 0.f;   // lane j holds h_j, c_j redundantly in every wave

  const float* x0 = inp + (size_t)b * DDIM;
  float xa = x0[lane];
  float xb = x0[64 + lane];

  // publish x-part pre-activations for step 0
  {
    float sx[5];
    xdots(xa, xb, WA, WB, sx);
    if (lane == 63){
      #pragma unroll
      for (int k = 0; k < 5; ++k) xpub_s[g][wbase + k] = sx[k] + bq[k];
    }
  }
  __syncthreads();

  #pragma unroll 1
  for (int t = 0; t < T_STEPS; ++t){
    if (t + 1 < T_STEPS){
      const float* nx = inp + ((size_t)(t+1) * BATCH + b) * DDIM;
      xa = nx[lane];
      xb = nx[64 + lane];
    }

    // ---- angles: lane-parallel (lane = wire). th = xpub + h-dot; ONE
    // v_cos + ONE v_sin cover all 10 wires; broadcast via readlane. ----
    float cs[NH], sn[NH];
    {
      float xr = xpub_s[g][lane & 15];
      float hdA = rdlane(h, 0) * wCT[0];
      float hdB = rdlane(h, 1) * wCT[1];
      hdA = fmaf(rdlane(h, 2), wCT[2], hdA);
      hdB = fmaf(rdlane(h, 3), wCT[3], hdB);
      hdA = fmaf(rdlane(h, 4), wCT[4], hdA);
      hdB = fmaf(rdlane(h, 5), wCT[5], hdB);
      hdA = fmaf(rdlane(h, 6), wCT[6], hdA);
      hdB = fmaf(rdlane(h, 7), wCT[7], hdB);
      hdA = fmaf(rdlane(h, 8), wCT[8], hdA);
      hdB = fmaf(rdlane(h, 9), wCT[9], hdB);
      float th = xr + (hdA + hdB);
      float cA = __builtin_amdgcn_cosf(th);
      float sA = __builtin_amdgcn_sinf(th);
      #pragma unroll
      for (int w = 0; w < NH; ++w){
        cs[w] = rdlane(cA, w);
        sn[w] = rdlane(sA, w);
      }
    }

    // ---- build half-statevector: u[j] = prod-state(x+p) at K j ----
    float f2 = pb2 ? sn[2] : cs[2];
    float f3 = pb3 ? sn[3] : cs[3];
    float f4 = pb4 ? sn[4] : cs[4];
    float f5 = pb5 ? sn[5] : cs[5];
    float m2345 = ((f2*f3)*(f4*f5)) * (a6w ? sn[6] : cs[6]);

    float q0 = (a0 ? sn[0] : cs[0]) * (a1 ? sn[1] : cs[1]);
    float q1 = (a0 ? cs[0] : sn[0]) * (a1 ? cs[1] : sn[1]);
    v2f ZZ; ZZ.x = m2345 * q0; ZZ.y = m2345 * q1;

    float u7  = half ? sn[7] : cs[7];
    float u7b = half ? cs[7] : sn[7];
    float t78[4];
    t78[0] = u7  * cs[8];   // k=0: R2=0,R1=0
    t78[1] = u7  * sn[8];   // k=1: R2=0,R1=1
    t78[2] = u7b * sn[8];   // k=2: R2=1,R1=0
    t78[3] = u7b * cs[8];   // k=3: R2=1,R1=1

    v2f s9a; s9a.x = cs[9]; s9a.y = sn[9];   // k even: b9 = R1^R0 = (0,1)
    v2f s9b; s9b.x = sn[9]; s9b.y = cs[9];   // k odd:  b9 = (1,0)

    v2f RE[NK], IM[NK];
    #pragma unroll
    for (int k = 0; k < NK; ++k){
      v2f M = (sp(t78[k]) * ((k & 1) ? s9b : s9a)) * ZZ;
      RE[k] = M * CRE[k];
      IM[k] = M * CIM[k];
    }

    // ---- RX(p), tau-form: lane wires 0..5 (all ds-pipe), reg wires 7..9 ----
    RX_LANE_T(dsx32, tq[0])
    RX_LANE_T(dsx16, tq[1])
    RX_LANE_T(dsx8,  tq[2])
    RX_LANE_T(dsx4,  tq[3])
    RX_LANE_T(dsx2,  tq[4])
    RX_LANE_T(dsx1,  tq[5])
    rx_reg_t<2>(tq[7], RE, IM);
    rx_reg_t<1>(tq[8], RE, IM);
    rx_reg9_t  (tq[9], RE, IM);

    // wire 6 (wave bit): exchange full half-state with partner wave via LDS
    Sx[g][half][0][lane] = make_float4(RE[0].x, RE[0].y, RE[1].x, RE[1].y);
    Sx[g][half][1][lane] = make_float4(RE[2].x, RE[2].y, RE[3].x, RE[3].y);
    Sx[g][half][2][lane] = make_float4(IM[0].x, IM[0].y, IM[1].x, IM[1].y);
    Sx[g][half][3][lane] = make_float4(IM[2].x, IM[2].y, IM[3].x, IM[3].y);

    // ---- shadow: x-part dots for step t+1 (uses prefetched x) ----
    float sx[5];
    xdots(xa, xb, WA, WB, sx);

    __syncthreads();   // barrier B: wire-6 exchange
    {
      float4 pr0 = Sx[g][half^1][0][lane];
      float4 pr1 = Sx[g][half^1][1][lane];
      float4 pi0 = Sx[g][half^1][2][lane];
      float4 pi1 = Sx[g][half^1][3][lane];
      v2f PR[NK], PI[NK];
      PR[0].x = pr0.x; PR[0].y = pr0.y; PR[1].x = pr0.z; PR[1].y = pr0.w;
      PR[2].x = pr1.x; PR[2].y = pr1.y; PR[3].x = pr1.z; PR[3].y = pr1.w;
      PI[0].x = pi0.x; PI[0].y = pi0.y; PI[1].x = pi0.z; PI[1].y = pi0.w;
      PI[2].x = pi1.x; PI[2].y = pi1.y; PI[3].x = pi1.z; PI[3].y = pi1.w;
      const v2f t6 = sp(tq[6]), n6 = sp(-tq[6]);
      #pragma unroll
      for (int k = 0; k < NK; ++k){
        RE[k] = PKFMA(t6, PI[k], RE[k]);
        IM[k] = PKFMA(n6, PR[k], IM[k]);
      }
    }

    // ---- PauliZ partials: packed |psi|^2 + shared pair-tree ----
    v2f Pk[NK];
    #pragma unroll
    for (int k = 0; k < NK; ++k) Pk[k] = PKFMA(RE[k], RE[k], IM[k] * IM[k]);
    float A0 = Pk[0].x + Pk[0].y, A1 = Pk[1].x + Pk[1].y;
    float A2 = Pk[2].x + Pk[2].y, A3 = Pk[3].x + Pk[3].y;
    float B0 = Pk[0].x - Pk[0].y, B1 = Pk[1].x - Pk[1].y;
    float B2 = Pk[2].x - Pk[2].y, B3 = Pk[3].x - Pk[3].y;
    float su = A0 + A1, sv = A2 + A3;
    float tot = su + sv;                 // plain sum
    float q4  = su - sv;                 // sign on R2
    float q6  = (A0 - A1) - (A2 - A3);   // sign parity of R2^R1 mask 0x6
    float q7  = (B0 - B1) - (B2 - B3);   // sign parity of mask 0x7

    // ---- shared signed-ladder reductions (sign masks encoded as add/sub) ----
    float a0p = LAD0_A(tot);
    float a0m = LAD0_S(tot);
    float b1pp = LAD1_A(a0p);
    float b1pm = LAD1_S(a0p);
    float b1mm = LAD1_S(a0m);
    float c2ppp = LAD2_A(b1pp);
    float c2ppm = LAD2_S(b1pp);
    float c2pmm = LAD2_S(b1pm);
    float c2mmm = LAD2_S(b1mm);
    float d1 = LAD3_A(c2ppp);   // P1: ++++ then --
    float d2 = LAD3_S(c2ppp);   // P2: +++-
    float d3 = LAD3_S(c2ppm);   // P3: ++--
    float d4 = LAD3_S(c2pmm);   // P4: +---
    float d5 = LAD3_S(c2mmm);   // P5: ----
    float P1 = LAD5_S(LAD4_S(d1));
    float P2 = LAD5_S(LAD4_S(d2));
    float P3 = LAD5_S(LAD4_S(d3));
    float P4 = LAD5_S(LAD4_S(d4));
    float P5 = LAD5_S(LAD4_S(d5));   // serves S5 (sigma +) and S6 (sigma -)
    // q7: P9 = all-minus (mask 0x3F); P0 = minus bits0-4, plus bit5 (0x1F)
    float e = LAD0_S(q7);
    e = LAD1_S(e); e = LAD2_S(e); e = LAD3_S(e); e = LAD4_S(e);
    float P9 = LAD5_S(e);
    float P0 = LAD5_A(e);
    // q4, q6: all-minus (mask 0x3F)
    float f_ = LAD0_S(q4);
    f_ = LAD1_S(f_); f_ = LAD2_S(f_); f_ = LAD3_S(f_); f_ = LAD4_S(f_);
    float P7 = LAD5_S(f_);
    float g_ = LAD0_S(q6);
    g_ = LAD1_S(g_); g_ = LAD2_S(g_); g_ = LAD3_S(g_); g_ = LAD4_S(g_);
    float P8 = LAD5_S(g_);

    if (lane == 63){
      float vals[10] = {P0,P1,P2,P3,P4,P5,P5,P7,P8,P9};
      #pragma unroll
      for (int j = 0; j < 10; ++j)
        ((float*)&partv[half][j])[g] = vals[j];
      #pragma unroll
      for (int k = 0; k < 5; ++k)
        xpub_s[g][wbase + k] = sx[k] + bq[k];
    }
    __syncthreads();   // barrier C: partials + next-step x-parts

    // ---- combine partials + activations + cell (every lane, every wave) ----
    float4 eL = partv[0][lane];
    float4 eH = partv[1][lane];
    float E0 = fmaf(sig, eH.x, eL.x);
    float E1 = fmaf(sig, eH.y, eL.y);
    float E2 = fmaf(sig, eH.z, eL.z);
    float E3 = fmaf(sig, eH.w, eL.w);
    float fv = 1.f / (1.f + __expf(-E0));
    float iv = 1.f / (1.f + __expf(-E1));
    float e2g = __expf(2.f * E2);
    float gv = (e2g - 1.f) / (e2g + 1.f);
    float ov = 1.f / (1.f + __expf(-E3));
    c = fmaf(fv, c, iv * gv);
    float e2c = __expf(2.f * c);
    h = ov * ((e2c - 1.f) / (e2c + 1.f));

    if (wv == 0 && lane < NH)
      out[((size_t)t * BATCH + b) * NH + lane] = h;
  }

  // hT, cT
  if (wv == 0 && lane < NH){
    const size_t ysN = (size_t)T_STEPS * BATCH * NH;
    out[ysN + (size_t)b * NH + lane]                      = h;
    out[ysN + (size_t)BATCH * NH + (size_t)b * NH + lane] = c;
  }
}

extern "C" void kernel_launch(void* const* d_in, const int* in_sizes, int n_in,
                              void* d_out, int out_size, void* d_ws, size_t ws_size,
                              hipStream_t stream)
{
  qlstm_kernel<<<BATCH, 512, 0, stream>>>(
      (const float*)d_in[0], (const float*)d_in[1],
      (const float*)d_in[2], (const float*)d_in[3],
      (const float*)d_in[4], (const float*)d_in[5],
      (const float*)d_in[6], (const float*)d_in[7],
      (const float*)d_in[8], (const float*)d_in[9],
      (float*)d_out);
}

// Round 7
// 753.451 us; speedup vs baseline: 1.3934x; 1.0469x over previous
//
#include <hip/hip_runtime.h>
#include <math.h>

#define T_STEPS 256
#define BATCH   256
#define DDIM    128
#define NH      10

typedef float v2f __attribute__((ext_vector_type(2)));
__device__ __forceinline__ v2f sp(float x){ v2f r; r.x = x; r.y = x; return r; }
#define PKFMA(a,b,c) __builtin_elementwise_fma((a),(b),(c))

// ---------- DPP helpers (VALU pipe) ----------
template<int CTRL, int RMASK, int BMASK>
__device__ __forceinline__ float dppz(float x){
  return __int_as_float(__builtin_amdgcn_update_dpp(
      0, __float_as_int(x), CTRL, RMASK, BMASK, true));
}
// Canonical wave64 ladder (proven R4+): lane 63 ends with the full sum.
__device__ __forceinline__ float red63(float v){
  v += dppz<0x111, 0xF, 0xF>(v);
  v += dppz<0x112, 0xF, 0xF>(v);
  v += dppz<0x114, 0xF, 0xE>(v);
  v += dppz<0x118, 0xF, 0xC>(v);
  v += dppz<0x142, 0xA, 0xF>(v);
  v += dppz<0x143, 0xC, 0xF>(v);
  return v;
}
__device__ __forceinline__ float rdlane(float v, int l){
  return __int_as_float(__builtin_amdgcn_readlane(__float_as_int(v), l));
}

// ---------- signed ladder stages (totals land at lane 63; proven R3) ----------
template<int CTRL,int RMASK,int BMASK>
__device__ __forceinline__ float lad_add(float v){ return v + dppz<CTRL,RMASK,BMASK>(v); }
template<int CTRL,int RMASK,int BMASK>
__device__ __forceinline__ float lad_sub(float v){ return dppz<CTRL,RMASK,BMASK>(v) - v; }
#define LAD0_A(v) lad_add<0x111,0xF,0xF>(v)
#define LAD0_S(v) lad_sub<0x111,0xF,0xF>(v)
#define LAD1_A(v) lad_add<0x112,0xF,0xF>(v)
#define LAD1_S(v) lad_sub<0x112,0xF,0xF>(v)
#define LAD2_A(v) lad_add<0x114,0xF,0xE>(v)
#define LAD2_S(v) lad_sub<0x114,0xF,0xE>(v)
#define LAD3_A(v) lad_add<0x118,0xF,0xC>(v)
#define LAD3_S(v) lad_sub<0x118,0xF,0xC>(v)
#define LAD4_A(v) lad_add<0x142,0xA,0xF>(v)
#define LAD4_S(v) lad_sub<0x142,0xA,0xF>(v)
#define LAD5_A(v) lad_add<0x143,0xC,0xF>(v)
#define LAD5_S(v) lad_sub<0x143,0xC,0xF>(v)

// ---------- ds-pipe xor fetchers (all 6 lane wires on the ds pipe) ----------
__device__ __forceinline__ float dsx32(float x){ return __shfl_xor(x, 32, 64); }
__device__ __forceinline__ float dsx16(float x){
  return __int_as_float(__builtin_amdgcn_ds_swizzle(__float_as_int(x), 0x401F));
}
__device__ __forceinline__ float dsx8(float x){
  return __int_as_float(__builtin_amdgcn_ds_swizzle(__float_as_int(x), 0x201F));
}
__device__ __forceinline__ float dsx4(float x){
  return __int_as_float(__builtin_amdgcn_ds_swizzle(__float_as_int(x), 0x101F));
}
__device__ __forceinline__ float dsx2(float x){
  return __int_as_float(__builtin_amdgcn_ds_swizzle(__float_as_int(x), 0x081F));
}
__device__ __forceinline__ float dsx1(float x){
  return __int_as_float(__builtin_amdgcn_ds_swizzle(__float_as_int(x), 0x041F));
}

#define NK 4   // 4 packed pairs = 8 complex amps per lane (half statevector)

// ---- tau-form RX: cosines folded into phase constants; ONE pk-FMA/output.
#define RX_LANE_T(FETCH, tv)                                                   \
  { const v2f tt_ = sp(tv), nt_ = sp(-(tv));                                   \
    _Pragma("unroll")                                                          \
    for (int k = 0; k < NK; ++k){                                              \
      v2f oa, ob;                                                              \
      oa.x = FETCH(RE[k].x); oa.y = FETCH(RE[k].y);                            \
      ob.x = FETCH(IM[k].x); ob.y = FETCH(IM[k].y);                            \
      RE[k] = PKFMA(tt_, ob, RE[k]);                                           \
      IM[k] = PKFMA(nt_, oa, IM[k]);                                           \
    } }

// RX on reg bit R2 (XB=2) / R1 (XB=1): partner pair is k^XB.
template<int XB>
__device__ __forceinline__ void rx_reg_t(float tv, v2f* RE, v2f* IM){
  const v2f tt = sp(tv), nt = sp(-tv);
  v2f oR[NK], oI[NK];
  #pragma unroll
  for (int k = 0; k < NK; ++k){ oR[k] = RE[k]; oI[k] = IM[k]; }
  #pragma unroll
  for (int k = 0; k < NK; ++k){
    RE[k] = PKFMA(tt, oI[k ^ XB], RE[k]);
    IM[k] = PKFMA(nt, oR[k ^ XB], IM[k]);
  }
}
// RX on reg bit R0: partner is the swapped component of the same pair.
__device__ __forceinline__ void rx_reg9_t(float tv, v2f* RE, v2f* IM){
  const v2f tt = sp(tv), nt = sp(-tv);
  #pragma unroll
  for (int k = 0; k < NK; ++k){
    v2f oa = __builtin_shufflevector(RE[k], RE[k], 1, 0);
    v2f ob = __builtin_shufflevector(IM[k], IM[k], 1, 0);
    RE[k] = PKFMA(tt, ob, RE[k]);
    IM[k] = PKFMA(nt, oa, IM[k]);
  }
}

// x-part dot products for the 5 owned wires: totals land at lane 63.
__device__ __forceinline__ void xdots(float xa, float xb,
                                      const v2f* WA, const v2f* WB, float* s){
  v2f xav = sp(xa), xbv = sp(xb);
  v2f p0 = PKFMA(xav, WA[0], xbv * WB[0]);
  v2f p1 = PKFMA(xav, WA[1], xbv * WB[1]);
  v2f p2 = PKFMA(xav, WA[2], xbv * WB[2]);
  s[0] = red63(p0.x); s[1] = red63(p0.y);
  s[2] = red63(p1.x); s[3] = red63(p1.y);
  s[4] = red63(p2.x);
}

// ================= R8 layout =================
// Wave pair per gate: 512 amps/wave = 64 lanes x 8 regs (4 v2f pairs).
// Wires 0..5 -> lane bits 5..0, wire 6 -> wave bit, wires 7,8,9 -> reg bits
// 2,1,0 (R0 = packed component).
// R7: wire-6 rotation applied FIRST (RX rotations commute). The partner
// half's initial PRODUCT state is built locally: flipping W flips only
// beta6 (m2345 factor swap) and beta7 (t78p[k] = t78[k^3]); phase shift
// collapses to sgn = (l0^R2)? + : -, folded with tau6 into init constants
// D6RE/D6IM. NO LDS exchange, NO barrier B -> 1 barrier/step.
__global__ void __launch_bounds__(512)
__attribute__((amdgpu_waves_per_eu(2)))
qlstm_kernel(const float* __restrict__ inp, const float* __restrict__ rxp,
             const float* __restrict__ Wf, const float* __restrict__ bf,
             const float* __restrict__ Wi, const float* __restrict__ bi,
             const float* __restrict__ Wg, const float* __restrict__ bg,
             const float* __restrict__ Wo, const float* __restrict__ bo,
             float* __restrict__ out)
{
  const int b    = blockIdx.x;
  const int tid  = threadIdx.x;
  const int wv   = tid >> 6;        // 0..7
  const int g    = wv >> 1;         // gate 0..3 (f,i,g,o)
  const int half = wv & 1;          // statevector half (wire-6 / wave bit)
  const int lane = tid & 63;

  // measurement partials, transposed: partv[half][j].{x,y,z,w} = gate f,i,g,o
  __shared__ float4 partv[2][64];
  // published x-part pre-activations (incl. bias), xpub_s[g][wire]
  __shared__ float xpub_s[4][16];
  ((float*)partv)[tid] = 0.f;       // 2*64*4 = 512 = blockDim

  const float* Wp = (g == 0) ? Wf : (g == 1) ? Wi : (g == 2) ? Wg : Wo;
  const float* bp = (g == 0) ? bf : (g == 1) ? bi : (g == 2) ? bg : bo;

  // Pre-scale weights by 0.5 (half-angle) * 1/(2pi) (v_sin/v_cos take
  // revolutions).
  const float WSC = 0.07957747154594767f;   // 1/(4*pi)

  // x-dot weights for this half's 5 owned wires (wbase..wbase+4)
  const int wbase = half * 5;
  v2f WA[3], WB[3];
  float bq[5];
  #pragma unroll
  for (int k = 0; k < 5; ++k) bq[k] = WSC * (bp[wbase + k] + rxp[wbase + k]);
  #pragma unroll
  for (int j = 0; j < 3; ++j){
    const int w0 = wbase + 2*j, w1 = wbase + 2*j + 1;
    WA[j].x = WSC * Wp[w0*138 + lane];
    WB[j].x = WSC * Wp[w0*138 + 64 + lane];
    if (2*j + 1 < 5){
      WA[j].y = WSC * Wp[w1*138 + lane];
      WB[j].y = WSC * Wp[w1*138 + 64 + lane];
    } else { WA[j].y = 0.f; WB[j].y = 0.f; }
  }
  // transposed h-weights: lane w holds W[w][128+j] (hdot computed lane-parallel)
  float wCT[NH];
  {
    const int row = (lane < NH) ? lane : 0;
    #pragma unroll
    for (int j = 0; j < NH; ++j){
      float v = WSC * Wp[row*138 + 128 + j];
      wCT[j] = (lane < NH) ? v : 0.f;
    }
  }

  // tau-form RX constants: tq[w] = tan(rxp[w]/2); PC = prod cos(rxp[w]/2)
  float tq[NH];
  float PC = 1.f;
  #pragma unroll
  for (int w = 0; w < NH; ++w){
    float th = 0.5f * rxp[w];
    float cw = cosf(th), sw = sinf(th);
    PC *= cw;
    tq[w] = sw / cw;
  }

  // ---- hoisted lane/wave constants ----
  const int l5 = (lane>>5)&1, l4 = (lane>>4)&1, l3 = (lane>>3)&1;
  const int l2 = (lane>>2)&1, l1 = (lane>>1)&1, l0 = lane&1;
  const int pb2 = l4^l3, pb3 = l3^l2, pb4 = l2^l1, pb5 = l1^l0;
  const int a0 = l5, a1 = l5^l4;
  const int a6w = l0 ^ half;                       // beta6
  const int n_base = pb2 + pb3 + pb4 + pb5 + a6w;

  // phase constants (-i)^k per reg (step-invariant), packed over R0, scaled
  // by PC. D6RE/D6IM = tau6 * sgn * (CIM, -CRE): the locally-built partner
  // half's contribution via the (applied-first) wire-6 rotation, where
  // sgn = (l0^R2)? + : - is the partner's phase shift (-i)^{+-2} collapse.
  v2f CRE[NK], CIM[NK], D6RE[NK], D6IM[NK];
  #pragma unroll
  for (int r = 0; r < 2*NK; ++r){
    const int R0 = r&1, R1 = (r>>1)&1, R2 = (r>>2)&1;
    int k = (n_base + (a0^R0) + (a1^R0) + (half^R2) + (R2^R1) + (R1^R0)) & 3;
    float cr = (k==0) ? PC : (k==2) ? -PC : 0.f;
    float ci = (k==1) ? -PC : (k==3) ? PC : 0.f;
    float sg6 = ((l0 ^ R2) & 1) ? tq[6] : -tq[6];
    float dre = sg6 * ci;
    float dim = -sg6 * cr;
    if (R0){ CRE[r>>1].y = cr;  CIM[r>>1].y = ci;
             D6RE[r>>1].y = dre; D6IM[r>>1].y = dim; }
    else   { CRE[r>>1].x = cr;  CIM[r>>1].x = ci;
             D6RE[r>>1].x = dre; D6IM[r>>1].x = dim; }
  }

  // wave-sign at combine: sigma = -1 for hidden units {0, 6..9}
  const float sig = (lane == 0 || lane >= 6) ? -1.f : 1.f;

  float h = 0.f, c = 0.f;   // lane j holds h_j, c_j redundantly in every wave

  const float* x0 = inp + (size_t)b * DDIM;
  float xa = x0[lane];
  float xb = x0[64 + lane];

  // publish x-part pre-activations for step 0
  {
    float sx[5];
    xdots(xa, xb, WA, WB, sx);
    if (lane == 63){
      #pragma unroll
      for (int k = 0; k < 5; ++k) xpub_s[g][wbase + k] = sx[k] + bq[k];
    }
  }
  __syncthreads();

  #pragma unroll 1
  for (int t = 0; t < T_STEPS; ++t){
    if (t + 1 < T_STEPS){
      const float* nx = inp + ((size_t)(t+1) * BATCH + b) * DDIM;
      xa = nx[lane];
      xb = nx[64 + lane];
    }

    // ---- angles: lane-parallel (lane = wire). th = xpub + h-dot; ONE
    // v_cos + ONE v_sin cover all 10 wires; broadcast via readlane. ----
    float cs[NH], sn[NH];
    {
      float xr = xpub_s[g][lane & 15];
      float hdA = rdlane(h, 0) * wCT[0];
      float hdB = rdlane(h, 1) * wCT[1];
      hdA = fmaf(rdlane(h, 2), wCT[2], hdA);
      hdB = fmaf(rdlane(h, 3), wCT[3], hdB);
      hdA = fmaf(rdlane(h, 4), wCT[4], hdA);
      hdB = fmaf(rdlane(h, 5), wCT[5], hdB);
      hdA = fmaf(rdlane(h, 6), wCT[6], hdA);
      hdB = fmaf(rdlane(h, 7), wCT[7], hdB);
      hdA = fmaf(rdlane(h, 8), wCT[8], hdA);
      hdB = fmaf(rdlane(h, 9), wCT[9], hdB);
      float th = xr + (hdA + hdB);
      float cA = __builtin_amdgcn_cosf(th);
      float sA = __builtin_amdgcn_sinf(th);
      #pragma unroll
      for (int w = 0; w < NH; ++w){
        cs[w] = rdlane(cA, w);
        sn[w] = rdlane(sA, w);
      }
    }

    // ---- build half-statevector WITH wire-6 mix folded (partner local) ----
    float f2 = pb2 ? sn[2] : cs[2];
    float f3 = pb3 ? sn[3] : cs[3];
    float f4 = pb4 ? sn[4] : cs[4];
    float f5 = pb5 ? sn[5] : cs[5];
    float m2345b = (f2*f3)*(f4*f5);
    float w6o = a6w ? sn[6] : cs[6];
    float w6p = a6w ? cs[6] : sn[6];
    float mo = m2345b * w6o;
    float mp = m2345b * w6p;

    float q0 = (a0 ? sn[0] : cs[0]) * (a1 ? sn[1] : cs[1]);
    float q1 = (a0 ? cs[0] : sn[0]) * (a1 ? cs[1] : sn[1]);
    v2f ZZ; ZZ.x = mo * q0; ZZ.y = mo * q1;
    v2f ZP; ZP.x = mp * q0; ZP.y = mp * q1;

    float u7  = half ? sn[7] : cs[7];
    float u7b = half ? cs[7] : sn[7];
    float t78[4];
    t78[0] = u7  * cs[8];   // k=0: R2=0,R1=0
    t78[1] = u7  * sn[8];   // k=1: R2=0,R1=1
    t78[2] = u7b * sn[8];   // k=2: R2=1,R1=0
    t78[3] = u7b * cs[8];   // k=3: R2=1,R1=1

    v2f s9a; s9a.x = cs[9]; s9a.y = sn[9];   // k even: b9 = R1^R0 = (0,1)
    v2f s9b; s9b.x = sn[9]; s9b.y = cs[9];   // k odd:  b9 = (1,0)

    v2f RE[NK], IM[NK];
    #pragma unroll
    for (int k = 0; k < NK; ++k){
      v2f s9v = (k & 1) ? s9b : s9a;
      v2f M  = (sp(t78[k])     * s9v) * ZZ;   // own half
      v2f Mp = (sp(t78[k ^ 3]) * s9v) * ZP;   // partner half (beta7 flip)
      RE[k] = PKFMA(Mp, D6RE[k], M * CRE[k]);
      IM[k] = PKFMA(Mp, D6IM[k], M * CIM[k]);
    }

    // ---- RX(p), tau-form: lane wires 0..5 (ds-pipe), reg wires 7..9 ----
    RX_LANE_T(dsx32, tq[0])
    RX_LANE_T(dsx16, tq[1])
    RX_LANE_T(dsx8,  tq[2])
    RX_LANE_T(dsx4,  tq[3])
    RX_LANE_T(dsx2,  tq[4])
    RX_LANE_T(dsx1,  tq[5])
    rx_reg_t<2>(tq[7], RE, IM);
    rx_reg_t<1>(tq[8], RE, IM);
    rx_reg9_t  (tq[9], RE, IM);

    // ---- shadow: x-part dots for step t+1 (uses prefetched x) ----
    float sx[5];
    xdots(xa, xb, WA, WB, sx);

    // ---- PauliZ partials: packed |psi|^2 + shared pair-tree ----
    v2f Pk[NK];
    #pragma unroll
    for (int k = 0; k < NK; ++k) Pk[k] = PKFMA(RE[k], RE[k], IM[k] * IM[k]);
    float A0 = Pk[0].x + Pk[0].y, A1 = Pk[1].x + Pk[1].y;
    float A2 = Pk[2].x + Pk[2].y, A3 = Pk[3].x + Pk[3].y;
    float B0 = Pk[0].x - Pk[0].y, B1 = Pk[1].x - Pk[1].y;
    float B2 = Pk[2].x - Pk[2].y, B3 = Pk[3].x - Pk[3].y;
    float su = A0 + A1, sv = A2 + A3;
    float tot = su + sv;                 // plain sum
    float q4  = su - sv;                 // sign on R2
    float q6  = (A0 - A1) - (A2 - A3);   // sign parity of R2^R1 mask 0x6
    float q7  = (B0 - B1) - (B2 - B3);   // sign parity of mask 0x7

    // ---- shared signed-ladder reductions (sign masks encoded as add/sub) ----
    float a0p = LAD0_A(tot);
    float a0m = LAD0_S(tot);
    float b1pp = LAD1_A(a0p);
    float b1pm = LAD1_S(a0p);
    float b1mm = LAD1_S(a0m);
    float c2ppp = LAD2_A(b1pp);
    float c2ppm = LAD2_S(b1pp);
    float c2pmm = LAD2_S(b1pm);
    float c2mmm = LAD2_S(b1mm);
    float d1 = LAD3_A(c2ppp);   // P1: ++++ then --
    float d2 = LAD3_S(c2ppp);   // P2: +++-
    float d3 = LAD3_S(c2ppm);   // P3: ++--
    float d4 = LAD3_S(c2pmm);   // P4: +---
    float d5 = LAD3_S(c2mmm);   // P5: ----
    float P1 = LAD5_S(LAD4_S(d1));
    float P2 = LAD5_S(LAD4_S(d2));
    float P3 = LAD5_S(LAD4_S(d3));
    float P4 = LAD5_S(LAD4_S(d4));
    float P5 = LAD5_S(LAD4_S(d5));   // serves S5 (sigma +) and S6 (sigma -)
    // q7: P9 = all-minus (mask 0x3F); P0 = minus bits0-4, plus bit5 (0x1F)
    float e = LAD0_S(q7);
    e = LAD1_S(e); e = LAD2_S(e); e = LAD3_S(e); e = LAD4_S(e);
    float P9 = LAD5_S(e);
    float P0 = LAD5_A(e);
    // q4, q6: all-minus (mask 0x3F)
    float f_ = LAD0_S(q4);
    f_ = LAD1_S(f_); f_ = LAD2_S(f_); f_ = LAD3_S(f_); f_ = LAD4_S(f_);
    float P7 = LAD5_S(f_);
    float g_ = LAD0_S(q6);
    g_ = LAD1_S(g_); g_ = LAD2_S(g_); g_ = LAD3_S(g_); g_ = LAD4_S(g_);
    float P8 = LAD5_S(g_);

    if (lane == 63){
      float vals[10] = {P0,P1,P2,P3,P4,P5,P5,P7,P8,P9};
      #pragma unroll
      for (int j = 0; j < 10; ++j)
        ((float*)&partv[half][j])[g] = vals[j];
      #pragma unroll
      for (int k = 0; k < 5; ++k)
        xpub_s[g][wbase + k] = sx[k] + bq[k];
    }
    __syncthreads();   // the ONLY barrier: partials + next-step x-parts

    // ---- combine partials + activations + cell (every lane, every wave) ----
    float4 eL = partv[0][lane];
    float4 eH = partv[1][lane];
    float E0 = fmaf(sig, eH.x, eL.x);
    float E1 = fmaf(sig, eH.y, eL.y);
    float E2 = fmaf(sig, eH.z, eL.z);
    float E3 = fmaf(sig, eH.w, eL.w);
    float fv = 1.f / (1.f + __expf(-E0));
    float iv = 1.f / (1.f + __expf(-E1));
    float e2g = __expf(2.f * E2);
    float gv = (e2g - 1.f) / (e2g + 1.f);
    float ov = 1.f / (1.f + __expf(-E3));
    c = fmaf(fv, c, iv * gv);
    float e2c = __expf(2.f * c);
    h = ov * ((e2c - 1.f) / (e2c + 1.f));

    if (wv == 0 && lane < NH)
      out[((size_t)t * BATCH + b) * NH + lane] = h;
  }

  // hT, cT
  if (wv == 0 && lane < NH){
    const size_t ysN = (size_t)T_STEPS * BATCH * NH;
    out[ysN + (size_t)b * NH + lane]                      = h;
    out[ysN + (size_t)BATCH * NH + (size_t)b * NH + lane] = c;
  }
}

extern "C" void kernel_launch(void* const* d_in, const int* in_sizes, int n_in,
                              void* d_out, int out_size, void* d_ws, size_t ws_size,
                              hipStream_t stream)
{
  qlstm_kernel<<<BATCH, 512, 0, stream>>>(
      (const float*)d_in[0], (const float*)d_in[1],
      (const float*)d_in[2], (const float*)d_in[3],
      (const float*)d_in[4], (const float*)d_in[5],
      (const float*)d_in[6], (const float*)d_in[7],
      (const float*)d_in[8], (const float*)d_in[9],
      (float*)d_out);
}